// Round 6
// baseline (38.918 us; speedup 1.0000x reference)
//
#include <hip/hip_runtime.h>
#include <math.h>

#define Bb 64
#define Ll 1024
#define Dd 512
#define Aa 512
#define NEG_INF -1e9f

#define LOG2E  1.4426950408889634f
#define LOG2E2 2.8853901617526703f   // 2*log2(e)

typedef float fx4 __attribute__((ext_vector_type(4)));

__device__ __forceinline__ float fast_exp2(float x) { return __builtin_amdgcn_exp2f(x); }
__device__ __forceinline__ float fast_rcp(float x)  { return __builtin_amdgcn_rcpf(x); }

// ---------------- K1: qb = dh @ W^T + bias;  vv2, scal ----------------
// grid (8, 64), 256 threads. Thread = quarter of one W row (64 rows/block).
__global__ __launch_bounds__(256) void k_qb(const float* __restrict__ dh,
                                            const float* __restrict__ W,
                                            const float* __restrict__ bias,
                                            const float* __restrict__ vw,
                                            const float* __restrict__ vg,
                                            const float* __restrict__ vb,
                                            const float* __restrict__ r,
                                            float* __restrict__ qb,
                                            float* __restrict__ vv2,
                                            float* __restrict__ scal) {
    __shared__ float h[Dd];
    __shared__ float red[4];
    const int b = blockIdx.y;
    const int c = blockIdx.x;            // a-chunk of 64 rows
    const int tid = threadIdx.x;
    const int a = c * 64 + (tid >> 2);
    const int quart = tid & 3;

    ((float2*)h)[tid] = ((const float2*)(dh + (size_t)b * Dd))[tid];
    __syncthreads();

    const float4* Wr = (const float4*)(W + (size_t)a * Dd + quart * 128);
    const float4* h4 = (const float4*)(h + quart * 128);
    float acc = 0.f;
    #pragma unroll 8
    for (int i = 0; i < 32; ++i) {
        float4 wq = Wr[i];
        float4 hv = h4[i];
        acc = fmaf(wq.x, hv.x, acc);
        acc = fmaf(wq.y, hv.y, acc);
        acc = fmaf(wq.z, hv.z, acc);
        acc = fmaf(wq.w, hv.w, acc);
    }
    acc += __shfl_xor(acc, 1);
    acc += __shfl_xor(acc, 2);
    if (quart == 0) qb[(size_t)b * Aa + a] = acc + bias[a];

    if (b == 0 && c == 0) {
        const int wave = tid >> 6, lane = tid & 63;
        float w0 = vw[tid], w1 = vw[tid + 256];
        float s = fmaf(w0, w0, w1 * w1);
        #pragma unroll
        for (int off = 32; off; off >>= 1) s += __shfl_xor(s, off);
        if (lane == 0) red[wave] = s;
        __syncthreads();
        float tot = red[0] + red[1] + red[2] + red[3];
        float inv = rsqrtf(tot);
        float g = vg[0];
        float vva0 = g * w0 * inv, vva1 = g * w1 * inv;
        vv2[tid] = 2.f * vva0;
        vv2[tid + 256] = 2.f * vva1;
        float s2 = vva0 + vva1;
        #pragma unroll
        for (int off = 32; off; off >>= 1) s2 += __shfl_xor(s2, off);
        __syncthreads();
        if (lane == 0) red[wave] = s2;
        __syncthreads();
        if (tid == 0)
            scal[0] = red[0] + red[1] + red[2] + red[3] + vb[0] + r[0];
    }
}

// ---------------- K2: p = masked sigmoid(energy + noise) ----------------
// grid (16, 64), 256 threads. Block covers 64 l; each wave: 2 batches x 8 rows.
#define TERMS(ACC, KA, KB, Q0, Q1, V0, V1)                                      \
    ACC = fmaf(V0.x, fast_rcp(fast_exp2(fmaf(KA.x, LOG2E2, Q0.x)) + 1.f), ACC); \
    ACC = fmaf(V0.y, fast_rcp(fast_exp2(fmaf(KA.y, LOG2E2, Q0.y)) + 1.f), ACC); \
    ACC = fmaf(V0.z, fast_rcp(fast_exp2(fmaf(KA.z, LOG2E2, Q0.z)) + 1.f), ACC); \
    ACC = fmaf(V0.w, fast_rcp(fast_exp2(fmaf(KA.w, LOG2E2, Q0.w)) + 1.f), ACC); \
    ACC = fmaf(V1.x, fast_rcp(fast_exp2(fmaf(KB.x, LOG2E2, Q1.x)) + 1.f), ACC); \
    ACC = fmaf(V1.y, fast_rcp(fast_exp2(fmaf(KB.y, LOG2E2, Q1.y)) + 1.f), ACC); \
    ACC = fmaf(V1.z, fast_rcp(fast_exp2(fmaf(KB.z, LOG2E2, Q1.z)) + 1.f), ACC); \
    ACC = fmaf(V1.w, fast_rcp(fast_exp2(fmaf(KB.w, LOG2E2, Q1.w)) + 1.f), ACC);

#define RED6(A)                    \
    A += __shfl_xor(A, 32);        \
    A += __shfl_xor(A, 16);        \
    A += __shfl_xor(A, 8);         \
    A += __shfl_xor(A, 4);         \
    A += __shfl_xor(A, 2);         \
    A += __shfl_xor(A, 1);

__global__ __launch_bounds__(256) void k_energy(const float* __restrict__ key,
                                                const float* __restrict__ noise,
                                                const float* __restrict__ mask,
                                                const float* __restrict__ qb,
                                                const float* __restrict__ vv2,
                                                const float* __restrict__ scal,
                                                float* __restrict__ p) {
    const int b = blockIdx.y;
    const int tid = threadIdx.x;
    const int wave = tid >> 6, lane = tid & 63;
    const int lblk = blockIdx.x * 64;                // block's first l (64 rows)

    const fx4* qb4 = (const fx4*)(qb + (size_t)b * Aa);
    fx4 q0 = qb4[lane];
    fx4 q1 = qb4[lane + 64];
    const fx4* v4 = (const fx4*)vv2;
    const fx4 v0 = v4[lane];
    const fx4 v1 = v4[lane + 64];
    const float ec = scal[0];
    q0 *= LOG2E2;
    q1 *= LOG2E2;

    const int lj = lane & 7;

    #pragma unroll 1
    for (int it = 0; it < 2; ++it) {
        const int lw0 = lblk + it * 32 + wave * 8;   // this batch's first l
        const int l = lw0 + lj;
        const float mk = mask[(size_t)b * Ll + l];
        const float nz = noise[(size_t)b * Ll + l];
        const float mn = (l == Ll - 1) ? 0.f : mask[(size_t)b * Ll + l + 1];

        const fx4* kp = (const fx4*)(key + ((size_t)b * Ll + lw0) * Aa);  // row = 128 fx4
        fx4 ka0 = kp[lane];           fx4 kb0 = kp[lane + 64];
        fx4 ka1 = kp[lane + 128];     fx4 kb1 = kp[lane + 192];
        fx4 ka2 = kp[lane + 256];     fx4 kb2 = kp[lane + 320];
        fx4 ka3 = kp[lane + 384];     fx4 kb3 = kp[lane + 448];
        fx4 ka4 = kp[lane + 512];     fx4 kb4 = kp[lane + 576];
        fx4 ka5 = kp[lane + 640];     fx4 kb5 = kp[lane + 704];
        fx4 ka6 = kp[lane + 768];     fx4 kb6 = kp[lane + 832];
        fx4 ka7 = kp[lane + 896];     fx4 kb7 = kp[lane + 960];
        __builtin_amdgcn_sched_barrier(0);   // loads stay above the compute

        float a0 = 0.f, a1 = 0.f, a2 = 0.f, a3 = 0.f, a4 = 0.f, a5 = 0.f, a6 = 0.f, a7 = 0.f;
        TERMS(a0, ka0, kb0, q0, q1, v0, v1)
        TERMS(a1, ka1, kb1, q0, q1, v0, v1)
        TERMS(a2, ka2, kb2, q0, q1, v0, v1)
        TERMS(a3, ka3, kb3, q0, q1, v0, v1)
        TERMS(a4, ka4, kb4, q0, q1, v0, v1)
        TERMS(a5, ka5, kb5, q0, q1, v0, v1)
        TERMS(a6, ka6, kb6, q0, q1, v0, v1)
        TERMS(a7, ka7, kb7, q0, q1, v0, v1)

        RED6(a0) RED6(a1) RED6(a2) RED6(a3) RED6(a4) RED6(a5) RED6(a6) RED6(a7)

        float sel = a0;
        sel = (lj == 1) ? a1 : sel;
        sel = (lj == 2) ? a2 : sel;
        sel = (lj == 3) ? a3 : sel;
        sel = (lj == 4) ? a4 : sel;
        sel = (lj == 5) ? a5 : sel;
        sel = (lj == 6) ? a6 : sel;
        sel = (lj == 7) ? a7 : sel;

        float e = (mk > 0.f) ? (ec - sel) : NEG_INF;
        float z = e + nz;
        float pv = fast_rcp(1.f + fast_exp2(-z * LOG2E));
        float em = mk * (1.f - mn);
        if (em > 0.f) pv = em;
        if (lane < 8) p[(size_t)b * Ll + l] = pv;
        __builtin_amdgcn_sched_barrier(0);   // no cross-batch register inflation
    }
}

// ---------------- K3: alpha = p * linear_recurrence ----------------
__global__ __launch_bounds__(64) void k_scan(const float* __restrict__ p,
                                             const float* __restrict__ prev,
                                             float* __restrict__ alpha) {
    const int b = blockIdx.x;
    const int lane = threadIdx.x;
    const float4* p4 = (const float4*)(p + (size_t)b * Ll);
    const float4* a4 = (const float4*)(prev + (size_t)b * Ll);

    float pr[16], pa[16];
    #pragma unroll
    for (int k = 0; k < 4; ++k) {
        float4 t = p4[lane * 4 + k];
        pr[k * 4 + 0] = t.x; pr[k * 4 + 1] = t.y; pr[k * 4 + 2] = t.z; pr[k * 4 + 3] = t.w;
        float4 u = a4[lane * 4 + k];
        pa[k * 4 + 0] = u.x; pa[k * 4 + 1] = u.y; pa[k * 4 + 2] = u.z; pa[k * 4 + 3] = u.w;
    }
    float pm1 = __shfl_up(pr[15], 1);
    if (lane == 0) pm1 = 0.f;

    float Ax = 1.f, Bx = 0.f;
    #pragma unroll
    for (int k = 0; k < 16; ++k) {
        float aj = 1.f - ((k == 0) ? pm1 : pr[k - 1]);
        Bx = fmaf(aj, Bx, pa[k]);
        Ax *= aj;
    }
    #pragma unroll
    for (int off = 1; off < 64; off <<= 1) {
        float pA = __shfl_up(Ax, off);
        float pB = __shfl_up(Bx, off);
        if (lane >= off) { Bx = fmaf(Ax, pB, Bx); Ax *= pA; }
    }
    float xin = __shfl_up(Bx, 1);
    if (lane == 0) xin = 0.f;

    float x = xin;
    float out[16];
    #pragma unroll
    for (int k = 0; k < 16; ++k) {
        float aj = 1.f - ((k == 0) ? pm1 : pr[k - 1]);
        x = fmaf(aj, x, pa[k]);
        out[k] = pr[k] * x;
    }
    float4* o4 = (float4*)(alpha + (size_t)b * Ll);
    #pragma unroll
    for (int k = 0; k < 4; ++k) {
        float4 t;
        t.x = out[k * 4 + 0]; t.y = out[k * 4 + 1]; t.z = out[k * 4 + 2]; t.w = out[k * 4 + 3];
        o4[lane * 4 + k] = t;
    }
}

extern "C" void kernel_launch(void* const* d_in, const int* in_sizes, int n_in,
                              void* d_out, int out_size, void* d_ws, size_t ws_size,
                              hipStream_t stream) {
    const float* dh    = (const float*)d_in[0];   // decoder_h [B,D]
    const float* key   = (const float*)d_in[1];   // key [B,L,A]
    // d_in[2] encoder_outputs — unused by the reference
    const float* prev  = (const float*)d_in[3];   // prev_att [B,L]
    const float* noise = (const float*)d_in[4];   // noise [B,L]
    const float* mask  = (const float*)d_in[5];   // mask [B,L]
    const float* W     = (const float*)d_in[6];   // W [A,D]
    const float* bias  = (const float*)d_in[7];   // b [A]
    const float* vw    = (const float*)d_in[8];   // v_weight [1,A]
    const float* vg    = (const float*)d_in[9];   // v_g [1]
    const float* vb    = (const float*)d_in[10];  // v_bias [1]
    const float* r     = (const float*)d_in[11];  // r [1]
    float* out = (float*)d_out;

    float* ws   = (float*)d_ws;
    float* vv2  = ws;                        // 512 floats
    float* scal = ws + Aa;                   // 1 float (padded to 1024)
    float* qb   = ws + 1024;                 // 64*512
    float* p    = ws + 1024 + Bb * Aa;       // 64*1024

    k_qb<<<dim3(8, Bb), 256, 0, stream>>>(dh, W, bias, vw, vg, vb, r, qb, vv2, scal);
    k_energy<<<dim3(Ll / 64, Bb), 256, 0, stream>>>(key, noise, mask, qb, vv2, scal, p);
    k_scan<<<Bb, 64, 0, stream>>>(p, prev, out);
}